// Round 16
// baseline (297.130 us; speedup 1.0000x reference)
//
#include <hip/hip_runtime.h>
#include <hip/hip_bf16.h>

#define N_NODES 50000
#define N_EDGES 800000
#define DIM 128
#define N_GRAPHS 512
#define NBUCK ((N_NODES + 63) / 64)      // 782 buckets of 64 nodes
#define CSRB 512                          // CSR barrier-group blocks
#define EPB ((N_EDGES + CSRB - 1) / CSRB) // 1563 edges per CSR block
#define GEMM_BLOCKS 782                   // ceil(ceil(50000/16)/4)

typedef unsigned int uint;
typedef unsigned short ushort;
typedef __attribute__((ext_vector_type(8))) short short8;   // 8 x bf16 MFMA frag
typedef __attribute__((ext_vector_type(4))) float f32x4;    // MFMA C/D frag

__device__ __forceinline__ ushort f2bf(float f) {
    uint u = __float_as_uint(f);
    uint r = (u + 0x7FFF + ((u >> 16) & 1)) >> 16;   // round-to-nearest-even
    return (ushort)r;
}
__device__ __forceinline__ uint pack2(float a, float b) {
    return (uint)f2bf(a) | ((uint)f2bf(b) << 16);
}
__device__ __forceinline__ float2 unpack2(uint v) {
    return make_float2(__uint_as_float(v << 16), __uint_as_float(v & 0xFFFF0000u));
}

// ---------------- kernel 1: zero bucketCnt + barrier + W -> MFMA B-frag order --------
// Wfrag uint index r = ((ct*4+kc)*64 + lane)*4 + j2 ; element j=2*j2(+1) has
// k = kc*32 + (lane>>4)*8 + j , n = ct*16 + (lane&15).

__global__ __launch_bounds__(256) void k_init(const float* __restrict__ W1,
                                              const float* __restrict__ W2,
                                              uint* __restrict__ wf1,
                                              uint* __restrict__ wf2,
                                              int* __restrict__ bucketCnt,
                                              int* __restrict__ bar) {
    int t = blockIdx.x * 256 + threadIdx.x;      // 64 blocks -> [0, 16384)
    if (t < NBUCK) bucketCnt[t] = 0;
    if (t >= NBUCK && t < NBUCK + 2) bar[t - NBUCK] = 0;   // barCnt, barGen
    const float* W = (t < 8192) ? W1 : W2;
    uint* dst = (t < 8192) ? wf1 : wf2;
    int r = t & 8191;
    int j2 = r & 3;
    int lane = (r >> 2) & 63;
    int tk = r >> 8;                 // ct*4+kc
    int kc = tk & 3, ct = tk >> 2;
    int j = j2 * 2;
    int k = kc * 32 + (lane >> 4) * 8 + j;
    int n = ct * 16 + (lane & 15);
    dst[r] = pack2(W[k * 128 + n], W[(k + 1) * 128 + n]);
}

// ---------------- device-scope spin barrier for the CSRB blocks ----------------
// (R10-proven pattern; all CSRB blocks co-resident: 512 blocks = 2/CU.)

__device__ __forceinline__ void gbar(int* barCnt, int* barGen, int phase) {
    __syncthreads();
    if (threadIdx.x == 0) {
        __threadfence();                                   // release
        if (atomicAdd(barCnt, 1) == CSRB - 1) {
            atomicExch(barCnt, 0);
            __threadfence();
            atomicAdd(barGen, 1);                          // gen -> phase+1
        } else {
            while (atomicAdd(barGen, 0) <= phase) {        // coherent RMW poll
                __builtin_amdgcn_s_sleep(2);
            }
        }
        __threadfence();                                   // acquire
    }
    __syncthreads();
}

// ---------------- GEMM device body ----------------
// SCALE=true : out = bf16((X@W) * dinv[r]);  SCALE=false: out = bf16(X@W)

template<bool BF16IN, bool SCALE>
__device__ __forceinline__ void gemm_body(int blk, const void* __restrict__ Xv,
                                          const uint* __restrict__ Wfrag,
                                          const float* __restrict__ dinv,
                                          uint* __restrict__ out, int N) {
    int wv = threadIdx.x >> 6, lane = threadIdx.x & 63;
    int strip = blk * 4 + wv;
    int row0 = strip * 16;
    if (row0 >= N) return;
    int m = lane & 15;        // A-row / D-col within tile
    int kg = lane >> 4;       // k-group
    int arow = row0 + m;
    bool valid = arow < N;

    short8 af[4];
    if constexpr (!BF16IN) {
        const float* X = (const float*)Xv;
        const float* base = X + (size_t)arow * DIM + kg * 8;
        #pragma unroll
        for (int kc = 0; kc < 4; ++kc) {
            float4 a0 = make_float4(0.f, 0.f, 0.f, 0.f), a1 = a0;
            if (valid) {
                a0 = *(const float4*)(base + kc * 32);
                a1 = *(const float4*)(base + kc * 32 + 4);
            }
            short8 f;
            f[0] = (short)f2bf(a0.x); f[1] = (short)f2bf(a0.y);
            f[2] = (short)f2bf(a0.z); f[3] = (short)f2bf(a0.w);
            f[4] = (short)f2bf(a1.x); f[5] = (short)f2bf(a1.y);
            f[6] = (short)f2bf(a1.z); f[7] = (short)f2bf(a1.w);
            af[kc] = f;
        }
    } else {
        const uint* X = (const uint*)Xv;
        const uint* base = X + (size_t)arow * 64 + kg * 4;
        #pragma unroll
        for (int kc = 0; kc < 4; ++kc) {
            union { uint4 u; short8 s; } cv;
            cv.u = valid ? *(const uint4*)(base + kc * 16) : make_uint4(0, 0, 0, 0);
            af[kc] = cv.s;
        }
    }

    f32x4 acc[8];
    #pragma unroll
    for (int ct = 0; ct < 8; ++ct) acc[ct] = (f32x4){0.f, 0.f, 0.f, 0.f};

    #pragma unroll
    for (int ct = 0; ct < 8; ++ct) {
        #pragma unroll
        for (int kc = 0; kc < 4; ++kc) {
            union { uint4 u; short8 s; } bv;
            bv.u = *(const uint4*)(Wfrag + ((size_t)(ct * 4 + kc) * 64 + lane) * 4);
            acc[ct] = __builtin_amdgcn_mfma_f32_16x16x32_bf16(af[kc], bv.s, acc[ct], 0, 0, 0);
        }
    }

    // epilogue: D row = kg*4 + reg, col = ct*16 + m
    ushort* ob = (ushort*)out;
    #pragma unroll
    for (int reg = 0; reg < 4; ++reg) {
        int orow = row0 + kg * 4 + reg;
        if (orow < N) {
            float di = SCALE ? dinv[orow] : 1.0f;
            size_t rb = (size_t)orow * DIM + m;
            #pragma unroll
            for (int ct = 0; ct < 8; ++ct)
                ob[rb + ct * 16] = f2bf(SCALE ? acc[ct][reg] * di : acc[ct][reg]);
        }
    }
}

// ---------------- kernel 2: fused CSR build (blocks 0..511, 4 barrier phases)
//                          || GEMM1 unscaled (blocks 512..1293, no barrier) ----------
// Phase 0: LDS histogram -> global bucketCnt   (hist SURVIVES in LDS)
// Phase 1: block 0 scans bucketCnt -> bucketStart/bucketCursor
// Phase 2: reserve runs from surviving LDS hist; scatter packed (src|dstlocal<<16)
// Phase 3: per-bucket local CSR (rowStart, dinv, csr), buckets strided over blocks.

__global__ __launch_bounds__(256) void k_build(const int* __restrict__ ei,
                                               int* __restrict__ bucketCnt,
                                               int* __restrict__ bucketStart,
                                               int* __restrict__ bucketCursor,
                                               uint* __restrict__ epk,
                                               int* __restrict__ rowStart,
                                               float* __restrict__ dinv,
                                               int* __restrict__ csr,
                                               int* __restrict__ bar,
                                               const float* __restrict__ x,
                                               const uint* __restrict__ wf1,
                                               uint* __restrict__ hs) {
    if (blockIdx.x >= CSRB) {
        gemm_body<false, false>(blockIdx.x - CSRB, x, wf1, nullptr, hs, N_NODES);
        return;
    }
    __shared__ int hc[NBUCK];
    __shared__ int hbase[NBUCK];
    __shared__ int wsum4[4];
    __shared__ int cnt[64];
    __shared__ int cur[64];
    int cb = blockIdx.x;
    int tid = threadIdx.x;
    int* barCnt = bar;
    int* barGen = bar + 1;
    int e0 = cb * EPB, e1 = min(e0 + EPB, N_EDGES);

    // ---- phase 0: histogram (LDS hist kept for phase 2) ----
    for (int t = tid; t < NBUCK; t += 256) hc[t] = 0;
    __syncthreads();
    for (int e = e0 + tid; e < e1; e += 256)
        atomicAdd(&hc[ei[N_EDGES + e] >> 6], 1);
    __syncthreads();
    for (int t = tid; t < NBUCK; t += 256) {
        int c = hc[t];
        if (c) atomicAdd(&bucketCnt[t], c);
    }
    gbar(barCnt, barGen, 0);

    // ---- phase 1: exclusive scan (block 0 only) ----
    if (cb == 0) {
        int base = tid * 4;
        int v[4];
        #pragma unroll
        for (int i = 0; i < 4; ++i)
            v[i] = (base + i < NBUCK) ? bucketCnt[base + i] : 0;
        int tot = v[0] + v[1] + v[2] + v[3];
        int lane = tid & 63, w = tid >> 6;
        int sc = tot;
        #pragma unroll
        for (int off = 1; off < 64; off <<= 1) {
            int u = __shfl_up(sc, off, 64);
            if (lane >= off) sc += u;
        }
        if (lane == 63) wsum4[w] = sc;
        __syncthreads();
        int woff = 0;
        #pragma unroll
        for (int ww = 0; ww < 4; ++ww) woff += (ww < w) ? wsum4[ww] : 0;
        int run = woff + sc - tot;
        #pragma unroll
        for (int i = 0; i < 4; ++i) {
            if (base + i < NBUCK) {
                bucketStart[base + i] = run;
                bucketCursor[base + i] = run;
            }
            run += v[i];
        }
        if (tid == 255) bucketStart[NBUCK] = run;
    }
    gbar(barCnt, barGen, 1);

    // ---- phase 2: reserve runs from surviving hist, then scatter ----
    for (int t = tid; t < NBUCK; t += 256) {
        int c = hc[t];
        hbase[t] = c ? atomicAdd(&bucketCursor[t], c) : 0;
        hc[t] = 0;
    }
    __syncthreads();
    for (int e = e0 + tid; e < e1; e += 256) {
        int s = ei[e], d = ei[N_EDGES + e];
        int b = d >> 6;
        int off = atomicAdd(&hc[b], 1);
        epk[hbase[b] + off] = (uint)s | ((uint)(d & 63) << 16);
    }
    gbar(barCnt, barGen, 2);

    // ---- phase 3: per-bucket local CSR ----
    for (int b = cb; b < NBUCK; b += CSRB) {
        int b0 = b << 6;
        int s = bucketStart[b], e = bucketStart[b + 1];
        if (tid < 64) cnt[tid] = 0;
        __syncthreads();
        for (int i = s + tid; i < e; i += 256)
            atomicAdd(&cnt[(epk[i] >> 16) & 63], 1);
        __syncthreads();
        if (tid < 64) {   // wave 0: 64-wide exclusive scan
            int c = cnt[tid];
            int sc = c;
            #pragma unroll
            for (int off = 1; off < 64; off <<= 1) {
                int u = __shfl_up(sc, off, 64);
                if (tid >= off) sc += u;
            }
            int excl = sc - c;
            int node = b0 + tid;
            if (node < N_NODES) {
                rowStart[node] = s + excl;
                dinv[node] = rsqrtf((float)c + 1.0f);
            }
            cur[tid] = s + excl;
        }
        if (tid == 0 && b == NBUCK - 1) rowStart[N_NODES] = e;
        __syncthreads();
        for (int i = s + tid; i < e; i += 256) {
            uint p = epk[i];
            int pos = atomicAdd(&cur[(p >> 16) & 63], 1);
            csr[pos] = (int)(p & 0xFFFFu);
        }
        __syncthreads();
    }
}

// ---------------- standalone GEMM2 (scaled epilogue; dinv ready) ----------------

__global__ __launch_bounds__(256) void k_lin2(const uint* __restrict__ Xb,
                                              const uint* __restrict__ Wfrag,
                                              const float* __restrict__ dinv,
                                              uint* __restrict__ out, int N) {
    gemm_body<true, true>(blockIdx.x, Xb, Wfrag, dinv, out, N);
}

// ---------------- Aggregation: full-wave gathers, 8/4/2/1 unroll ladder ----------------
// wave = one node; lane holds cols (2l, 2l+1) packed bf16. Edge indices are
// wave-uniform -> csr and dinv[src] loads scalarize.
// SCALE_SRC=true : rows unscaled h; acc += h[src]*dinv[src] (+ self*dinv[i])
// SCALE_SRC=false: rows pre-scaled;  acc += row[src] (+ self)
// out = relu(acc*dinv[i] + bias) -> row bf16, or fused head dot -> y[nid].

template<bool FUSE_HEAD, bool SCALE_SRC>
__global__ __launch_bounds__(256) void k_aggregate(const uint* __restrict__ HS,
                                                   const int* __restrict__ rowStart,
                                                   const int* __restrict__ csr,
                                                   const float* __restrict__ dinv,
                                                   const float* __restrict__ bias,
                                                   const float* __restrict__ Wl,
                                                   uint* __restrict__ outRow,
                                                   float* __restrict__ outY, int n) {
    int wv = threadIdx.x >> 6, lane = threadIdx.x & 63;
    int nid = blockIdx.x * 4 + wv;
    if (nid >= n) return;
    float di = dinv[nid];
    float2 acc = unpack2(HS[(size_t)nid * 64 + lane]);   // self contribution
    if constexpr (SCALE_SRC) { acc.x *= di; acc.y *= di; }
    int beg = rowStart[nid], end = rowStart[nid + 1];
    int e = beg;
    for (; e + 7 < end; e += 8) {
        int s0 = csr[e],     s1 = csr[e + 1], s2 = csr[e + 2], s3 = csr[e + 3];
        int s4 = csr[e + 4], s5 = csr[e + 5], s6 = csr[e + 6], s7 = csr[e + 7];
        float2 f0 = unpack2(HS[(size_t)s0 * 64 + lane]);
        float2 f1 = unpack2(HS[(size_t)s1 * 64 + lane]);
        float2 f2 = unpack2(HS[(size_t)s2 * 64 + lane]);
        float2 f3 = unpack2(HS[(size_t)s3 * 64 + lane]);
        float2 f4 = unpack2(HS[(size_t)s4 * 64 + lane]);
        float2 f5 = unpack2(HS[(size_t)s5 * 64 + lane]);
        float2 f6 = unpack2(HS[(size_t)s6 * 64 + lane]);
        float2 f7 = unpack2(HS[(size_t)s7 * 64 + lane]);
        if constexpr (SCALE_SRC) {
            float d0 = dinv[s0], d1 = dinv[s1], d2 = dinv[s2], d3 = dinv[s3];
            float d4 = dinv[s4], d5 = dinv[s5], d6 = dinv[s6], d7 = dinv[s7];
            acc.x += ((f0.x * d0 + f1.x * d1) + (f2.x * d2 + f3.x * d3))
                   + ((f4.x * d4 + f5.x * d5) + (f6.x * d6 + f7.x * d7));
            acc.y += ((f0.y * d0 + f1.y * d1) + (f2.y * d2 + f3.y * d3))
                   + ((f4.y * d4 + f5.y * d5) + (f6.y * d6 + f7.y * d7));
        } else {
            acc.x += ((f0.x + f1.x) + (f2.x + f3.x)) + ((f4.x + f5.x) + (f6.x + f7.x));
            acc.y += ((f0.y + f1.y) + (f2.y + f3.y)) + ((f4.y + f5.y) + (f6.y + f7.y));
        }
    }
    if (e + 3 < end) {
        int s0 = csr[e], s1 = csr[e + 1], s2 = csr[e + 2], s3 = csr[e + 3];
        float2 f0 = unpack2(HS[(size_t)s0 * 64 + lane]);
        float2 f1 = unpack2(HS[(size_t)s1 * 64 + lane]);
        float2 f2 = unpack2(HS[(size_t)s2 * 64 + lane]);
        float2 f3 = unpack2(HS[(size_t)s3 * 64 + lane]);
        if constexpr (SCALE_SRC) {
            float d0 = dinv[s0], d1 = dinv[s1], d2 = dinv[s2], d3 = dinv[s3];
            acc.x += (f0.x * d0 + f1.x * d1) + (f2.x * d2 + f3.x * d3);
            acc.y += (f0.y * d0 + f1.y * d1) + (f2.y * d2 + f3.y * d3);
        } else {
            acc.x += (f0.x + f1.x) + (f2.x + f3.x);
            acc.y += (f0.y + f1.y) + (f2.y + f3.y);
        }
        e += 4;
    }
    if (e + 1 < end) {
        int s0 = csr[e], s1 = csr[e + 1];
        float2 f0 = unpack2(HS[(size_t)s0 * 64 + lane]);
        float2 f1 = unpack2(HS[(size_t)s1 * 64 + lane]);
        if constexpr (SCALE_SRC) {
            float d0 = dinv[s0], d1 = dinv[s1];
            acc.x += f0.x * d0 + f1.x * d1;
            acc.y += f0.y * d0 + f1.y * d1;
        } else {
            acc.x += f0.x + f1.x;
            acc.y += f0.y + f1.y;
        }
        e += 2;
    }
    if (e < end) {
        int s0 = csr[e];
        float2 f0 = unpack2(HS[(size_t)s0 * 64 + lane]);
        if constexpr (SCALE_SRC) {
            float d0 = dinv[s0];
            acc.x += f0.x * d0;
            acc.y += f0.y * d0;
        } else {
            acc.x += f0.x;
            acc.y += f0.y;
        }
    }
    int c = lane * 2;
    float ox = fmaxf(acc.x * di + bias[c], 0.f);
    float oy = fmaxf(acc.y * di + bias[c + 1], 0.f);
    if constexpr (!FUSE_HEAD) {
        outRow[(size_t)nid * 64 + lane] = pack2(ox, oy);
    } else {
        float part = ox * Wl[c] + oy * Wl[c + 1];
        #pragma unroll
        for (int off = 32; off > 0; off >>= 1) part += __shfl_down(part, off, 64);
        if (lane == 0) outY[nid] = part;
    }
}

// ---------------- Pool over per-node head values ----------------

__global__ __launch_bounds__(64) void k_pool_y(const float* __restrict__ y,
                                               const int* __restrict__ batch,
                                               const float* __restrict__ bl,
                                               float* __restrict__ out, int n) {
    int g = blockIdx.x;
    int lane = threadIdx.x;
    int lo = 0, hi = n;
    while (lo < hi) { int mid = (lo + hi) >> 1; if (batch[mid] < g) lo = mid + 1; else hi = mid; }
    int s = lo;
    hi = n;
    while (lo < hi) { int mid = (lo + hi) >> 1; if (batch[mid] < g + 1) lo = mid + 1; else hi = mid; }
    int e = lo;

    float sum = 0.f;
    for (int i = s + lane; i < e; i += 64) sum += y[i];
    #pragma unroll
    for (int off = 32; off > 0; off >>= 1) sum += __shfl_down(sum, off, 64);
    if (lane == 0) out[g] = sum / fmaxf((float)(e - s), 1.0f) + bl[0];
}

// ---------------- launch ----------------

extern "C" void kernel_launch(void* const* d_in, const int* in_sizes, int n_in,
                              void* d_out, int out_size, void* d_ws, size_t ws_size,
                              hipStream_t stream) {
    const float* x  = (const float*)d_in[0];
    const int*   ei = (const int*)d_in[1];
    const int*   batch = (const int*)d_in[2];
    const float* W1 = (const float*)d_in[3];
    const float* b1 = (const float*)d_in[4];
    const float* W2 = (const float*)d_in[5];
    const float* b2 = (const float*)d_in[6];
    const float* Wl = (const float*)d_in[7];
    const float* bl = (const float*)d_in[8];
    float* out = (float*)d_out;

    // workspace layout (uint units; starts kept 16B-aligned)
    uint* hs  = (uint*)d_ws;                             // N*64 (bf16 x128 rows)
    uint* h2b = hs + (size_t)N_NODES * 64;               // N*64
    float* dinv = (float*)(h2b + (size_t)N_NODES * 64);  // N
    float* ynode = dinv + N_NODES;                       // N
    int* rowStart = (int*)(ynode + N_NODES);             // N+4
    int* bucketCnt = rowStart + N_NODES + 4;             // 788
    int* bucketStart = bucketCnt + 788;                  // 788
    int* bucketCursor = bucketStart + 788;               // 788
    int* bar = bucketCursor + 788;                       // 4 (barCnt, barGen)
    int* csr = bar + 4;                                  // E
    uint* epk = (uint*)(csr + N_EDGES);                  // E packed words
    uint* wf1 = epk + N_EDGES;                           // 8192
    uint* wf2 = wf1 + 8192;                              // 8192

    // 1. zero bucketCnt + barrier + weight conversion
    k_init<<<64, 256, 0, stream>>>(W1, W2, wf1, wf2, bucketCnt, bar);

    // 2. fused CSR build (4 barrier phases, 512 blocks) || GEMM1 (782 blocks)
    k_build<<<CSRB + GEMM_BLOCKS, 256, 0, stream>>>(
        ei, bucketCnt, bucketStart, bucketCursor, epk, rowStart, dinv, csr, bar,
        x, wf1, hs);

    int aggGrid = (N_NODES + 3) / 4;

    // 3. layer 1 aggregation (applies dinv to unscaled h rows)
    k_aggregate<false, true><<<aggGrid, 256, 0, stream>>>(
        hs, rowStart, csr, dinv, b1, Wl, h2b, ynode, N_NODES);

    // 4. layer 2 GEMM (scaled epilogue)
    k_lin2<<<GEMM_BLOCKS, 256, 0, stream>>>(h2b, wf2, dinv, hs, N_NODES);

    // 5. layer 2 aggregation + fused head
    k_aggregate<true, false><<<aggGrid, 256, 0, stream>>>(
        hs, rowStart, csr, dinv, b2, Wl, h2b, ynode, N_NODES);

    // 6. pool + head bias
    k_pool_y<<<N_GRAPHS, 64, 0, stream>>>(ynode, batch, bl, out, N_NODES);
}

// Round 17
// 142.239 us; speedup vs baseline: 2.0889x; 2.0889x over previous
//
#include <hip/hip_runtime.h>
#include <hip/hip_bf16.h>

#define N_NODES 50000
#define N_EDGES 800000
#define DIM 128
#define N_GRAPHS 512
#define NBUCK ((N_NODES + 63) / 64)      // 782 buckets of 64 nodes
#define SC_CH 2048                        // edges per scatter block
#define SCT_BLOCKS ((N_EDGES + SC_CH - 1) / SC_CH)   // 391
#define GEMM_BLOCKS 782                   // ceil(ceil(50000/16)/4)

typedef unsigned int uint;
typedef unsigned short ushort;
typedef __attribute__((ext_vector_type(8))) short short8;   // 8 x bf16 MFMA frag
typedef __attribute__((ext_vector_type(4))) float f32x4;    // MFMA C/D frag

__device__ __forceinline__ ushort f2bf(float f) {
    uint u = __float_as_uint(f);
    uint r = (u + 0x7FFF + ((u >> 16) & 1)) >> 16;   // round-to-nearest-even
    return (ushort)r;
}
__device__ __forceinline__ uint pack2(float a, float b) {
    return (uint)f2bf(a) | ((uint)f2bf(b) << 16);
}
__device__ __forceinline__ float2 unpack2(uint v) {
    return make_float2(__uint_as_float(v << 16), __uint_as_float(v & 0xFFFF0000u));
}

// ---------------- kernel 1: zero bucketCnt + W -> MFMA B-frag order ----------------
// Wfrag uint index r = ((ct*4+kc)*64 + lane)*4 + j2 ; element j=2*j2(+1) has
// k = kc*32 + (lane>>4)*8 + j , n = ct*16 + (lane&15).

__global__ __launch_bounds__(256) void k_init(const float* __restrict__ W1,
                                              const float* __restrict__ W2,
                                              uint* __restrict__ wf1,
                                              uint* __restrict__ wf2,
                                              int* __restrict__ bucketCnt) {
    int t = blockIdx.x * 256 + threadIdx.x;      // 64 blocks -> [0, 16384)
    if (t < NBUCK) bucketCnt[t] = 0;
    const float* W = (t < 8192) ? W1 : W2;
    uint* dst = (t < 8192) ? wf1 : wf2;
    int r = t & 8191;
    int j2 = r & 3;
    int lane = (r >> 2) & 63;
    int tk = r >> 8;                 // ct*4+kc
    int kc = tk & 3, ct = tk >> 2;
    int j = j2 * 2;
    int k = kc * 32 + (lane >> 4) * 8 + j;
    int n = ct * 16 + (lane & 15);
    dst[r] = pack2(W[k * 128 + n], W[(k + 1) * 128 + n]);
}

// ---------------- kernel 2: LDS histogram -> global bucketCnt ----------------

__global__ __launch_bounds__(1024) void k_bcount(const int* __restrict__ ei,
                                                 int* __restrict__ bucketCnt, int E) {
    __shared__ int h[NBUCK];
    int tid = threadIdx.x;
    for (int t = tid; t < NBUCK; t += 1024) h[t] = 0;
    __syncthreads();
    for (int e = blockIdx.x * 1024 + tid; e < E; e += gridDim.x * 1024)
        atomicAdd(&h[ei[E + e] >> 6], 1);
    __syncthreads();
    for (int t = tid; t < NBUCK; t += 1024) {
        int c = h[t];
        if (c) atomicAdd(&bucketCnt[t], c);
    }
}

// ---------------- kernel 3: exclusive scan of bucketCnt (1 block, 1 load round) -------

__global__ __launch_bounds__(256) void k_bscan(const int* __restrict__ bucketCnt,
                                               int* __restrict__ bucketStart,
                                               int* __restrict__ bucketCursor) {
    __shared__ int wsum4[4];
    int tid = threadIdx.x;
    int base = tid * 4;
    int v[4];
    #pragma unroll
    for (int i = 0; i < 4; ++i)
        v[i] = (base + i < NBUCK) ? bucketCnt[base + i] : 0;
    int tot = v[0] + v[1] + v[2] + v[3];
    int lane = tid & 63, w = tid >> 6;
    int sc = tot;
    #pragma unroll
    for (int off = 1; off < 64; off <<= 1) {
        int u = __shfl_up(sc, off, 64);
        if (lane >= off) sc += u;
    }
    if (lane == 63) wsum4[w] = sc;
    __syncthreads();
    int woff = 0;
    #pragma unroll
    for (int ww = 0; ww < 4; ++ww) woff += (ww < w) ? wsum4[ww] : 0;
    int run = woff + sc - tot;
    #pragma unroll
    for (int i = 0; i < 4; ++i) {
        if (base + i < NBUCK) {
            bucketStart[base + i] = run;
            bucketCursor[base + i] = run;
        }
        run += v[i];
    }
    if (tid == 255) bucketStart[NBUCK] = run;
}

// ---------------- GEMM device body ----------------
// SCALE=true : out = bf16((X@W) * dinv[r]);  SCALE=false: out = bf16(X@W)

template<bool BF16IN, bool SCALE>
__device__ __forceinline__ void gemm_body(int blk, const void* __restrict__ Xv,
                                          const uint* __restrict__ Wfrag,
                                          const float* __restrict__ dinv,
                                          uint* __restrict__ out, int N) {
    int wv = threadIdx.x >> 6, lane = threadIdx.x & 63;
    int strip = blk * 4 + wv;
    int row0 = strip * 16;
    if (row0 >= N) return;
    int m = lane & 15;        // A-row / D-col within tile
    int kg = lane >> 4;       // k-group
    int arow = row0 + m;
    bool valid = arow < N;

    short8 af[4];
    if constexpr (!BF16IN) {
        const float* X = (const float*)Xv;
        const float* base = X + (size_t)arow * DIM + kg * 8;
        #pragma unroll
        for (int kc = 0; kc < 4; ++kc) {
            float4 a0 = make_float4(0.f, 0.f, 0.f, 0.f), a1 = a0;
            if (valid) {
                a0 = *(const float4*)(base + kc * 32);
                a1 = *(const float4*)(base + kc * 32 + 4);
            }
            short8 f;
            f[0] = (short)f2bf(a0.x); f[1] = (short)f2bf(a0.y);
            f[2] = (short)f2bf(a0.z); f[3] = (short)f2bf(a0.w);
            f[4] = (short)f2bf(a1.x); f[5] = (short)f2bf(a1.y);
            f[6] = (short)f2bf(a1.z); f[7] = (short)f2bf(a1.w);
            af[kc] = f;
        }
    } else {
        const uint* X = (const uint*)Xv;
        const uint* base = X + (size_t)arow * 64 + kg * 4;
        #pragma unroll
        for (int kc = 0; kc < 4; ++kc) {
            union { uint4 u; short8 s; } cv;
            cv.u = valid ? *(const uint4*)(base + kc * 16) : make_uint4(0, 0, 0, 0);
            af[kc] = cv.s;
        }
    }

    f32x4 acc[8];
    #pragma unroll
    for (int ct = 0; ct < 8; ++ct) acc[ct] = (f32x4){0.f, 0.f, 0.f, 0.f};

    #pragma unroll
    for (int ct = 0; ct < 8; ++ct) {
        #pragma unroll
        for (int kc = 0; kc < 4; ++kc) {
            union { uint4 u; short8 s; } bv;
            bv.u = *(const uint4*)(Wfrag + ((size_t)(ct * 4 + kc) * 64 + lane) * 4);
            acc[ct] = __builtin_amdgcn_mfma_f32_16x16x32_bf16(af[kc], bv.s, acc[ct], 0, 0, 0);
        }
    }

    // epilogue: D row = kg*4 + reg, col = ct*16 + m
    ushort* ob = (ushort*)out;
    #pragma unroll
    for (int reg = 0; reg < 4; ++reg) {
        int orow = row0 + kg * 4 + reg;
        if (orow < N) {
            float di = SCALE ? dinv[orow] : 1.0f;
            size_t rb = (size_t)orow * DIM + m;
            #pragma unroll
            for (int ct = 0; ct < 8; ++ct)
                ob[rb + ct * 16] = f2bf(SCALE ? acc[ct][reg] * di : acc[ct][reg]);
        }
    }
}

// ---------------- kernel 4: scatter (blocks 0..390) || GEMM1 unscaled (391..1172) ----
// Direct scatter, small 2048-edge chunks -> 391 blocks keep all CUs busy after
// GEMM1 drains (R14 lesson: scatter is latency-bound, not write-bound).

__global__ __launch_bounds__(256) void k_mega1(const int* __restrict__ ei,
                                               int* __restrict__ bucketCursor,
                                               uint* __restrict__ epk,
                                               const float* __restrict__ x,
                                               const uint* __restrict__ wf1,
                                               uint* __restrict__ hs) {
    __shared__ int hc[NBUCK];
    __shared__ int hbase[NBUCK];
    if (blockIdx.x >= SCT_BLOCKS) {
        gemm_body<false, false>(blockIdx.x - SCT_BLOCKS, x, wf1, nullptr, hs, N_NODES);
        return;
    }
    int tid = threadIdx.x;
    int e0 = blockIdx.x * SC_CH;
    int e1 = min(e0 + SC_CH, N_EDGES);
    for (int t = tid; t < NBUCK; t += 256) hc[t] = 0;
    __syncthreads();
    for (int e = e0 + tid; e < e1; e += 256)
        atomicAdd(&hc[ei[N_EDGES + e] >> 6], 1);
    __syncthreads();
    for (int t = tid; t < NBUCK; t += 256) {
        int c = hc[t];
        hbase[t] = c ? atomicAdd(&bucketCursor[t], c) : 0;
        hc[t] = 0;
    }
    __syncthreads();
    for (int e = e0 + tid; e < e1; e += 256) {
        int s = ei[e], d = ei[N_EDGES + e];
        int b = d >> 6;
        int off = atomicAdd(&hc[b], 1);
        epk[hbase[b] + off] = (uint)s | ((uint)(d & 63) << 16);
    }
}

// ---------------- kernel 5: per-bucket local CSR (full 782-block grid) ----------------

__global__ __launch_bounds__(256) void k_localcsr(const uint* __restrict__ epk,
                                                  const int* __restrict__ bucketStart,
                                                  int* __restrict__ rowStart,
                                                  float* __restrict__ dinv,
                                                  int* __restrict__ csr) {
    __shared__ int cnt[64];
    __shared__ int cur[64];
    int tid = threadIdx.x;
    int b = blockIdx.x;
    int b0 = b << 6;
    int s = bucketStart[b], e = bucketStart[b + 1];
    if (tid < 64) cnt[tid] = 0;
    __syncthreads();
    for (int i = s + tid; i < e; i += 256)
        atomicAdd(&cnt[(epk[i] >> 16) & 63], 1);
    __syncthreads();
    if (tid < 64) {   // wave 0: 64-wide exclusive scan
        int c = cnt[tid];
        int sc = c;
        #pragma unroll
        for (int off = 1; off < 64; off <<= 1) {
            int u = __shfl_up(sc, off, 64);
            if (tid >= off) sc += u;
        }
        int excl = sc - c;
        int node = b0 + tid;
        if (node < N_NODES) {
            rowStart[node] = s + excl;
            dinv[node] = rsqrtf((float)c + 1.0f);
        }
        cur[tid] = s + excl;
    }
    if (tid == 0 && b == NBUCK - 1) rowStart[N_NODES] = e;
    __syncthreads();
    for (int i = s + tid; i < e; i += 256) {
        uint p = epk[i];
        int pos = atomicAdd(&cur[(p >> 16) & 63], 1);
        csr[pos] = (int)(p & 0xFFFFu);
    }
}

// ---------------- standalone GEMM2 (scaled epilogue; dinv ready) ----------------

__global__ __launch_bounds__(256) void k_lin2(const uint* __restrict__ Xb,
                                              const uint* __restrict__ Wfrag,
                                              const float* __restrict__ dinv,
                                              uint* __restrict__ out, int N) {
    gemm_body<true, true>(blockIdx.x, Xb, Wfrag, dinv, out, N);
}

// ---------------- Aggregation: full-wave gathers, 8/4/2/1 unroll ladder ----------------
// wave = one node; lane holds cols (2l, 2l+1) packed bf16. Edge indices are
// wave-uniform -> csr and dinv[src] loads scalarize.
// SCALE_SRC=true : rows unscaled h; acc += h[src]*dinv[src] (+ self*dinv[i])
// SCALE_SRC=false: rows pre-scaled;  acc += row[src] (+ self)
// out = relu(acc*dinv[i] + bias) -> row bf16, or fused head dot -> y[nid].

template<bool FUSE_HEAD, bool SCALE_SRC>
__global__ __launch_bounds__(256) void k_aggregate(const uint* __restrict__ HS,
                                                   const int* __restrict__ rowStart,
                                                   const int* __restrict__ csr,
                                                   const float* __restrict__ dinv,
                                                   const float* __restrict__ bias,
                                                   const float* __restrict__ Wl,
                                                   uint* __restrict__ outRow,
                                                   float* __restrict__ outY, int n) {
    int wv = threadIdx.x >> 6, lane = threadIdx.x & 63;
    int nid = blockIdx.x * 4 + wv;
    if (nid >= n) return;
    float di = dinv[nid];
    float2 acc = unpack2(HS[(size_t)nid * 64 + lane]);   // self contribution
    if constexpr (SCALE_SRC) { acc.x *= di; acc.y *= di; }
    int beg = rowStart[nid], end = rowStart[nid + 1];
    int e = beg;
    for (; e + 7 < end; e += 8) {
        int s0 = csr[e],     s1 = csr[e + 1], s2 = csr[e + 2], s3 = csr[e + 3];
        int s4 = csr[e + 4], s5 = csr[e + 5], s6 = csr[e + 6], s7 = csr[e + 7];
        float2 f0 = unpack2(HS[(size_t)s0 * 64 + lane]);
        float2 f1 = unpack2(HS[(size_t)s1 * 64 + lane]);
        float2 f2 = unpack2(HS[(size_t)s2 * 64 + lane]);
        float2 f3 = unpack2(HS[(size_t)s3 * 64 + lane]);
        float2 f4 = unpack2(HS[(size_t)s4 * 64 + lane]);
        float2 f5 = unpack2(HS[(size_t)s5 * 64 + lane]);
        float2 f6 = unpack2(HS[(size_t)s6 * 64 + lane]);
        float2 f7 = unpack2(HS[(size_t)s7 * 64 + lane]);
        if constexpr (SCALE_SRC) {
            float d0 = dinv[s0], d1 = dinv[s1], d2 = dinv[s2], d3 = dinv[s3];
            float d4 = dinv[s4], d5 = dinv[s5], d6 = dinv[s6], d7 = dinv[s7];
            acc.x += ((f0.x * d0 + f1.x * d1) + (f2.x * d2 + f3.x * d3))
                   + ((f4.x * d4 + f5.x * d5) + (f6.x * d6 + f7.x * d7));
            acc.y += ((f0.y * d0 + f1.y * d1) + (f2.y * d2 + f3.y * d3))
                   + ((f4.y * d4 + f5.y * d5) + (f6.y * d6 + f7.y * d7));
        } else {
            acc.x += ((f0.x + f1.x) + (f2.x + f3.x)) + ((f4.x + f5.x) + (f6.x + f7.x));
            acc.y += ((f0.y + f1.y) + (f2.y + f3.y)) + ((f4.y + f5.y) + (f6.y + f7.y));
        }
    }
    if (e + 3 < end) {
        int s0 = csr[e], s1 = csr[e + 1], s2 = csr[e + 2], s3 = csr[e + 3];
        float2 f0 = unpack2(HS[(size_t)s0 * 64 + lane]);
        float2 f1 = unpack2(HS[(size_t)s1 * 64 + lane]);
        float2 f2 = unpack2(HS[(size_t)s2 * 64 + lane]);
        float2 f3 = unpack2(HS[(size_t)s3 * 64 + lane]);
        if constexpr (SCALE_SRC) {
            float d0 = dinv[s0], d1 = dinv[s1], d2 = dinv[s2], d3 = dinv[s3];
            acc.x += (f0.x * d0 + f1.x * d1) + (f2.x * d2 + f3.x * d3);
            acc.y += (f0.y * d0 + f1.y * d1) + (f2.y * d2 + f3.y * d3);
        } else {
            acc.x += (f0.x + f1.x) + (f2.x + f3.x);
            acc.y += (f0.y + f1.y) + (f2.y + f3.y);
        }
        e += 4;
    }
    if (e + 1 < end) {
        int s0 = csr[e], s1 = csr[e + 1];
        float2 f0 = unpack2(HS[(size_t)s0 * 64 + lane]);
        float2 f1 = unpack2(HS[(size_t)s1 * 64 + lane]);
        if constexpr (SCALE_SRC) {
            float d0 = dinv[s0], d1 = dinv[s1];
            acc.x += f0.x * d0 + f1.x * d1;
            acc.y += f0.y * d0 + f1.y * d1;
        } else {
            acc.x += f0.x + f1.x;
            acc.y += f0.y + f1.y;
        }
        e += 2;
    }
    if (e < end) {
        int s0 = csr[e];
        float2 f0 = unpack2(HS[(size_t)s0 * 64 + lane]);
        if constexpr (SCALE_SRC) {
            float d0 = dinv[s0];
            acc.x += f0.x * d0;
            acc.y += f0.y * d0;
        } else {
            acc.x += f0.x;
            acc.y += f0.y;
        }
    }
    int c = lane * 2;
    float ox = fmaxf(acc.x * di + bias[c], 0.f);
    float oy = fmaxf(acc.y * di + bias[c + 1], 0.f);
    if constexpr (!FUSE_HEAD) {
        outRow[(size_t)nid * 64 + lane] = pack2(ox, oy);
    } else {
        float part = ox * Wl[c] + oy * Wl[c + 1];
        #pragma unroll
        for (int off = 32; off > 0; off >>= 1) part += __shfl_down(part, off, 64);
        if (lane == 0) outY[nid] = part;
    }
}

// ---------------- Pool over per-node head values ----------------

__global__ __launch_bounds__(64) void k_pool_y(const float* __restrict__ y,
                                               const int* __restrict__ batch,
                                               const float* __restrict__ bl,
                                               float* __restrict__ out, int n) {
    int g = blockIdx.x;
    int lane = threadIdx.x;
    int lo = 0, hi = n;
    while (lo < hi) { int mid = (lo + hi) >> 1; if (batch[mid] < g) lo = mid + 1; else hi = mid; }
    int s = lo;
    hi = n;
    while (lo < hi) { int mid = (lo + hi) >> 1; if (batch[mid] < g + 1) lo = mid + 1; else hi = mid; }
    int e = lo;

    float sum = 0.f;
    for (int i = s + lane; i < e; i += 64) sum += y[i];
    #pragma unroll
    for (int off = 32; off > 0; off >>= 1) sum += __shfl_down(sum, off, 64);
    if (lane == 0) out[g] = sum / fmaxf((float)(e - s), 1.0f) + bl[0];
}

// ---------------- launch ----------------

extern "C" void kernel_launch(void* const* d_in, const int* in_sizes, int n_in,
                              void* d_out, int out_size, void* d_ws, size_t ws_size,
                              hipStream_t stream) {
    const float* x  = (const float*)d_in[0];
    const int*   ei = (const int*)d_in[1];
    const int*   batch = (const int*)d_in[2];
    const float* W1 = (const float*)d_in[3];
    const float* b1 = (const float*)d_in[4];
    const float* W2 = (const float*)d_in[5];
    const float* b2 = (const float*)d_in[6];
    const float* Wl = (const float*)d_in[7];
    const float* bl = (const float*)d_in[8];
    float* out = (float*)d_out;

    // workspace layout (uint units; starts kept 16B-aligned)
    uint* hs  = (uint*)d_ws;                             // N*64 (bf16 x128 rows)
    uint* h2b = hs + (size_t)N_NODES * 64;               // N*64
    float* dinv = (float*)(h2b + (size_t)N_NODES * 64);  // N
    float* ynode = dinv + N_NODES;                       // N
    int* rowStart = (int*)(ynode + N_NODES);             // N+4
    int* bucketCnt = rowStart + N_NODES + 4;             // 788
    int* bucketStart = bucketCnt + 788;                  // 788
    int* bucketCursor = bucketStart + 788;               // 788
    int* csr = bucketCursor + 788;                       // E
    uint* epk = (uint*)(csr + N_EDGES);                  // E packed words
    uint* wf1 = epk + N_EDGES;                           // 8192
    uint* wf2 = wf1 + 8192;                              // 8192

    // 1. zero bucketCnt + weight conversion
    k_init<<<64, 256, 0, stream>>>(W1, W2, wf1, wf2, bucketCnt);

    // 2. bucket histogram (LDS + global atomics)
    k_bcount<<<64, 1024, 0, stream>>>(ei, bucketCnt, N_EDGES);

    // 3. exclusive scan (1 block, single load round)
    k_bscan<<<1, 256, 0, stream>>>(bucketCnt, bucketStart, bucketCursor);

    // 4. scatter (391 small chunks) || GEMM1 (unscaled, independent of CSR)
    k_mega1<<<SCT_BLOCKS + GEMM_BLOCKS, 256, 0, stream>>>(ei, bucketCursor, epk, x, wf1, hs);

    // 5. per-bucket local CSR
    k_localcsr<<<NBUCK, 256, 0, stream>>>(epk, bucketStart, rowStart, dinv, csr);

    int aggGrid = (N_NODES + 3) / 4;

    // 6. layer 1 aggregation (applies dinv to unscaled h rows)
    k_aggregate<false, true><<<aggGrid, 256, 0, stream>>>(
        hs, rowStart, csr, dinv, b1, Wl, h2b, ynode, N_NODES);

    // 7. layer 2 GEMM (scaled epilogue)
    k_lin2<<<GEMM_BLOCKS, 256, 0, stream>>>(h2b, wf2, dinv, hs, N_NODES);

    // 8. layer 2 aggregation + fused head
    k_aggregate<true, false><<<aggGrid, 256, 0, stream>>>(
        hs, rowStart, csr, dinv, b2, Wl, h2b, ynode, N_NODES);

    // 9. pool + head bias
    k_pool_y<<<N_GRAPHS, 64, 0, stream>>>(ynode, batch, bl, out, N_NODES);
}